// Round 1
// baseline (3358.199 us; speedup 1.0000x reference)
//
#include <hip/hip_runtime.h>

// SALSA3D: C=64, Ci=16, D=8, H=W=160, K=3, S=2, P=1 -> nH=nW=80, L=6400, F=144
// Pipeline: proj(mid slice) -> unfold -> flash attention (fp32) -> fold/norm -> final add
//
// ws layout (floats):
//   P3  at 0         : [2][3][16][25600] = 2,457,600   (dead after k_unfold)
//   Pat at 2,457,600 : [2][3][6400][144] = 5,529,600
//   zi2 at 7,987,200 : [2][16][25600]    =   819,200
//   Zi  at 0 (reuses P3 space): [2][6400][144] = 1,843,200 (< P3 size, and < Pat offset)
// total = 35.2 MB

#define NPIX 25600
#define SCALE 10.0f

// ---------------- K1: 1x1x1 conv projections at mid depth ----------------
__global__ void k_proj(const float* __restrict__ b,
                       const float* __restrict__ gw, const float* __restrict__ gb,
                       const float* __restrict__ thw, const float* __restrict__ thb,
                       const float* __restrict__ phw, const float* __restrict__ phb,
                       float* __restrict__ P3) {
    __shared__ float Wl[3 * 1024];
    __shared__ float Bl[48];
    int tid = threadIdx.x;
    int g = blockIdx.y;
    int pix = blockIdx.x * 256 + tid;
    for (int i = tid; i < 1024; i += 256) {
        Wl[i]        = gw[i];   // s=0: query source (g_w)
        Wl[1024 + i] = phw[i];  // s=1: key source   (phi_w)
        Wl[2048 + i] = thw[i];  // s=2: value source (theta_w)
    }
    if (tid < 16) { Bl[tid] = gb[tid]; Bl[16 + tid] = phb[tid]; Bl[32 + tid] = thb[tid]; }
    __syncthreads();

    float acc[48];
#pragma unroll
    for (int o = 0; o < 48; o++) acc[o] = 0.f;
    const float* bp = b + (size_t)g * 64 * 8 * NPIX + (size_t)4 * NPIX + pix;
    for (int c = 0; c < 64; c++) {
        float xv = bp[(size_t)c * 8 * NPIX];
#pragma unroll
        for (int o = 0; o < 48; o++)
            acc[o] += Wl[(o >> 4) * 1024 + (o & 15) * 64 + c] * xv;  // LDS broadcast
    }
#pragma unroll
    for (int o = 0; o < 48; o++)
        P3[(size_t)(g * 48 + o) * NPIX + pix] = acc[o] + Bl[o];
}

// ---------------- K2: unfold to patch matrices [gs][l][f] ----------------
__global__ void k_unfold(const float* __restrict__ P3, float* __restrict__ Pat) {
    int idx = blockIdx.x * 256 + threadIdx.x;  // 2*3*6400*144 exact
    int f = idx % 144;
    int l = (idx / 144) % 6400;
    int gs = idx / (144 * 6400);
    int ci = f / 9, kr = (f % 9) / 3, kc = f % 3;
    int oh = l / 80, ow = l % 80;
    int h = oh * 2 + kr - 1, w = ow * 2 + kc - 1;
    float v = 0.f;
    if (h >= 0 && h < 160 && w >= 0 && w < 160)
        v = P3[(size_t)(gs * 16 + ci) * NPIX + h * 160 + w];
    Pat[idx] = v;
}

// ---------------- K3: flash attention, fp32 vector ALU ----------------
// Block: 256 threads, 32 queries. Thread t: query row tr=t>>3, col group cg=t&7
// (4 key cols per tile of 32), O feature slice fo=cg*18 (18 of 144).
__global__ __launch_bounds__(256) void k_attn(const float* __restrict__ Pat,
                                              float* __restrict__ Zi) {
    __shared__ float Qs[32 * 146];
    __shared__ float Ks[32 * 146];
    __shared__ float Vs[32 * 146];
    int tid = threadIdx.x;
    int g = blockIdx.y;
    int qbase = blockIdx.x * 32;
    const float* Qp = Pat + (size_t)(g * 3 + 0) * 6400 * 144;
    const float* Kp = Pat + (size_t)(g * 3 + 1) * 6400 * 144;
    const float* Vp = Pat + (size_t)(g * 3 + 2) * 6400 * 144;

    for (int i = tid; i < 32 * 144; i += 256) {
        int r = i / 144, f = i % 144;
        Qs[r * 146 + f] = Qp[(qbase + r) * 144 + f];
    }

    int tr = tid >> 3;
    int cg = tid & 7;
    int fo = cg * 18;
    float m = -1e30f, lp = 0.f;
    float O[18];
#pragma unroll
    for (int u = 0; u < 18; u++) O[u] = 0.f;

    for (int kt = 0; kt < 200; kt++) {
        int kb = kt * 32;
        __syncthreads();
        for (int i = tid; i < 32 * 144; i += 256) {
            int r = i / 144, f = i % 144;
            Ks[r * 146 + f] = Kp[(kb + r) * 144 + f];
            Vs[r * 146 + f] = Vp[(kb + r) * 144 + f];
        }
        __syncthreads();

        float s0 = 0.f, s1 = 0.f, s2 = 0.f, s3 = 0.f;
        for (int f = 0; f < 144; f++) {
            float qv = Qs[tr * 146 + f];
            s0 += qv * Ks[(cg * 4 + 0) * 146 + f];
            s1 += qv * Ks[(cg * 4 + 1) * 146 + f];
            s2 += qv * Ks[(cg * 4 + 2) * 146 + f];
            s3 += qv * Ks[(cg * 4 + 3) * 146 + f];
        }
        s0 *= SCALE; s1 *= SCALE; s2 *= SCALE; s3 *= SCALE;

        float mt = fmaxf(fmaxf(s0, s1), fmaxf(s2, s3));
        mt = fmaxf(mt, __shfl_xor(mt, 1, 64));
        mt = fmaxf(mt, __shfl_xor(mt, 2, 64));
        mt = fmaxf(mt, __shfl_xor(mt, 4, 64));
        float mnew = fmaxf(m, mt);
        float alpha = __expf(m - mnew);
        float p4[4];
        p4[0] = __expf(s0 - mnew);
        p4[1] = __expf(s1 - mnew);
        p4[2] = __expf(s2 - mnew);
        p4[3] = __expf(s3 - mnew);
        lp = lp * alpha + (p4[0] + p4[1] + p4[2] + p4[3]);
        m = mnew;
#pragma unroll
        for (int u = 0; u < 18; u++) O[u] *= alpha;

        // P @ V: broadcast p across the 8 row-threads, accumulate O slice
        for (int cc4 = 0; cc4 < 8; cc4++) {
            int src = (tid & ~7) | cc4;
#pragma unroll
            for (int j = 0; j < 4; j++) {
                float pv = __shfl(p4[j], src, 64);
                int cc = cc4 * 4 + j;
#pragma unroll
                for (int u = 0; u < 18; u++)
                    O[u] += pv * Vs[cc * 146 + fo + u];
            }
        }
    }

    float lf = lp;
    lf += __shfl_xor(lf, 1, 64);
    lf += __shfl_xor(lf, 2, 64);
    lf += __shfl_xor(lf, 4, 64);
    float inv = 1.f / lf;
    float* zr = Zi + ((size_t)g * 6400 + qbase + tr) * 144 + fo;
#pragma unroll
    for (int u = 0; u < 18; u++) zr[u] = O[u] * inv;
}

// ---------------- K4: fold (overlap-add) + mask normalization ----------------
__global__ void k_fold(const float* __restrict__ Zi, float* __restrict__ zi2) {
    int idx = blockIdx.x * 256 + threadIdx.x;  // 2*16*25600 exact
    int pix = idx % NPIX;
    int ci = (idx / NPIX) & 15;
    int g = idx / (16 * NPIX);
    int h = pix / 160, w = pix % 160;
    int ohs[2], krs[2], nh = 0;
#pragma unroll
    for (int kr = 0; kr < 3; kr++) {
        int t = h + 1 - kr;
        if (t >= 0 && (t & 1) == 0 && (t >> 1) < 80) { ohs[nh] = t >> 1; krs[nh] = kr; nh++; }
    }
    int ows[2], kcs[2], nw = 0;
#pragma unroll
    for (int kc = 0; kc < 3; kc++) {
        int t = w + 1 - kc;
        if (t >= 0 && (t & 1) == 0 && (t >> 1) < 80) { ows[nw] = t >> 1; kcs[nw] = kc; nw++; }
    }
    float s = 0.f;
    for (int a = 0; a < nh; a++)
        for (int bb = 0; bb < nw; bb++) {
            int l = ohs[a] * 80 + ows[bb];
            int f = ci * 9 + krs[a] * 3 + kcs[bb];
            s += Zi[((size_t)g * 6400 + l) * 144 + f];
        }
    zi2[idx] = s / (float)(nh * nw);
}

// ---------------- K5: out = b + conv1x1(zi2 broadcast over D) ----------------
__global__ void k_final(const float* __restrict__ b, const float* __restrict__ zi2,
                        const float* __restrict__ Ww, const float* __restrict__ Wb,
                        float* __restrict__ out) {
    __shared__ float z[16 * 64];
    __shared__ float Wl[64 * 16];
    __shared__ float Bl[64];
    int tid = threadIdx.x;
    int g = blockIdx.y;
    int pxb = blockIdx.x * 64;
    for (int i = tid; i < 1024; i += 256) {
        int ci = i >> 6, px = i & 63;
        z[i] = zi2[(size_t)(g * 16 + ci) * NPIX + pxb + px];
        Wl[i] = Ww[i];
    }
    if (tid < 64) Bl[tid] = Wb[tid];
    __syncthreads();

    int px4 = tid & 15;   // which float4 of the 64-pixel chunk
    int cg = tid >> 4;    // c = cg + 16*c4
    float acc[4][4];
#pragma unroll
    for (int c4 = 0; c4 < 4; c4++) {
        float bv = Bl[cg + 16 * c4];
#pragma unroll
        for (int j = 0; j < 4; j++) acc[c4][j] = bv;
    }
#pragma unroll
    for (int ci = 0; ci < 16; ci++) {
        float zv[4];
#pragma unroll
        for (int j = 0; j < 4; j++) zv[j] = z[ci * 64 + px4 * 4 + j];
#pragma unroll
        for (int c4 = 0; c4 < 4; c4++) {
            float wv = Wl[(cg + 16 * c4) * 16 + ci];
#pragma unroll
            for (int j = 0; j < 4; j++) acc[c4][j] += wv * zv[j];
        }
    }
    for (int d = 0; d < 8; d++) {
#pragma unroll
        for (int c4 = 0; c4 < 4; c4++) {
            int c = cg + 16 * c4;
            size_t base = ((size_t)(g * 64 + c) * 8 + d) * NPIX + pxb + px4 * 4;
            float4 bv = *(const float4*)(b + base);
            float4 ov = make_float4(bv.x + acc[c4][0], bv.y + acc[c4][1],
                                    bv.z + acc[c4][2], bv.w + acc[c4][3]);
            *(float4*)(out + base) = ov;
        }
    }
}

extern "C" void kernel_launch(void* const* d_in, const int* in_sizes, int n_in,
                              void* d_out, int out_size, void* d_ws, size_t ws_size,
                              hipStream_t stream) {
    const float* b   = (const float*)d_in[0];
    const float* gw  = (const float*)d_in[1];
    const float* gb  = (const float*)d_in[2];
    const float* thw = (const float*)d_in[3];
    const float* thb = (const float*)d_in[4];
    const float* phw = (const float*)d_in[5];
    const float* phb = (const float*)d_in[6];
    const float* Ww  = (const float*)d_in[7];
    const float* Wb  = (const float*)d_in[8];
    float* out = (float*)d_out;
    float* ws = (float*)d_ws;

    float* P3  = ws;                       // 2,457,600 floats
    float* Pat = ws + 2457600;             // 5,529,600 floats
    float* zi2 = ws + 2457600 + 5529600;   //   819,200 floats
    float* Zi  = ws;                       // reuses P3 region (1,843,200 floats)

    k_proj<<<dim3(100, 2), 256, 0, stream>>>(b, gw, gb, thw, thb, phw, phb, P3);
    k_unfold<<<dim3(21600), 256, 0, stream>>>(P3, Pat);
    k_attn<<<dim3(200, 2), 256, 0, stream>>>(Pat, Zi);
    k_fold<<<dim3(3200), 256, 0, stream>>>(Zi, zi2);
    k_final<<<dim3(400, 2), 256, 0, stream>>>(b, zi2, Ww, Wb, out);
}

// Round 2
// 453.563 us; speedup vs baseline: 7.4040x; 7.4040x over previous
//
#include <hip/hip_runtime.h>

// SALSA3D: C=64, Ci=16, D=8, H=W=160, K=3, S=2, P=1 -> nH=nW=80, L=6400, F=144
// proj -> unfold(bf16 Q/K row-major, V^T f-major) -> MFMA flash attn (S^T=K@Q^T,
// ksplit=4, bf16 partials) -> merge -> fold/norm -> final add
//
// ws layout (float offsets), with lifetime-based overlays:
//   PatQK bf16 [2][2][6400][144]            f[0        .. 1,843,200)  dead after attn
//   VT    bf16 [2][144][6400]               f[1,843,200.. 2,764,800)  dead after attn
//   ml    f32  [2][4][6400]x2               f[2,764,800.. 2,867,200)
//   P3    f32  [2][3][16][25600]            f[2,867,200.. 5,324,800)  dead after unfold
//   Opart bf16 [2][4][6400][144]            f[2,867,200.. 6,553,600)  overlays P3
//   Zi    f32  [2][6400][144]               f[0        .. 1,843,200)  overlays PatQK
//   zi2   f32  [2][16][25600]               f[1,843,200.. 2,662,400)  overlays VT
// high-water 6,553,600 floats = 26.2 MB

#define NPIX 25600
#define LOG2E10 14.42695040888963f  // 10 * log2(e): softmax_scale folded into exp2

typedef float floatx16 __attribute__((ext_vector_type(16)));
typedef short short8 __attribute__((ext_vector_type(8)));

__device__ inline unsigned short f2bf(float x) {
    union { float f; unsigned int u; } v; v.f = x;
    unsigned int r = v.u + 0x7fffu + ((v.u >> 16) & 1u);
    return (unsigned short)(r >> 16);
}
__device__ inline float bf2f(unsigned short u) {
    union { unsigned int u; float f; } v; v.u = ((unsigned int)u) << 16;
    return v.f;
}

// ---------------- K1: 1x1x1 conv projections at mid depth ----------------
__global__ void k_proj(const float* __restrict__ b,
                       const float* __restrict__ gw, const float* __restrict__ gb,
                       const float* __restrict__ thw, const float* __restrict__ thb,
                       const float* __restrict__ phw, const float* __restrict__ phb,
                       float* __restrict__ P3) {
    __shared__ float Wl[3 * 1024];
    __shared__ float Bl[48];
    int tid = threadIdx.x;
    int g = blockIdx.y;
    int pix = blockIdx.x * 256 + tid;
    for (int i = tid; i < 1024; i += 256) {
        Wl[i]        = gw[i];   // s=0: query source (g_w)
        Wl[1024 + i] = phw[i];  // s=1: key source   (phi_w)
        Wl[2048 + i] = thw[i];  // s=2: value source (theta_w)
    }
    if (tid < 16) { Bl[tid] = gb[tid]; Bl[16 + tid] = phb[tid]; Bl[32 + tid] = thb[tid]; }
    __syncthreads();

    float acc[48];
#pragma unroll
    for (int o = 0; o < 48; o++) acc[o] = 0.f;
    const float* bp = b + (size_t)g * 64 * 8 * NPIX + (size_t)4 * NPIX + pix;
    for (int c = 0; c < 64; c++) {
        float xv = bp[(size_t)c * 8 * NPIX];
#pragma unroll
        for (int o = 0; o < 48; o++)
            acc[o] += Wl[(o >> 4) * 1024 + (o & 15) * 64 + c] * xv;
    }
#pragma unroll
    for (int o = 0; o < 48; o++)
        P3[(size_t)(g * 48 + o) * NPIX + pix] = acc[o] + Bl[o];
}

// ---------------- K2a: unfold Q,K -> bf16 [g][s][l][144] ----------------
__global__ void k_unfold_qk(const float* __restrict__ P3, unsigned short* __restrict__ Pat) {
    int idx = blockIdx.x * 256 + threadIdx.x;  // 2*2*6400*144 exact
    int f = idx % 144;
    int l = (idx / 144) % 6400;
    int s = (idx / (144 * 6400)) & 1;
    int g = idx / (2 * 144 * 6400);
    int ci = f / 9, kr = (f % 9) / 3, kc = f % 3;
    int oh = l / 80, ow = l % 80;
    int h = oh * 2 + kr - 1, w = ow * 2 + kc - 1;
    float v = 0.f;
    if (h >= 0 && h < 160 && w >= 0 && w < 160)
        v = P3[(size_t)(g * 48 + s * 16 + ci) * NPIX + h * 160 + w];
    Pat[idx] = f2bf(v);
}

// ---------------- K2b: unfold V transposed -> bf16 [g][144][6400] ----------------
__global__ void k_unfold_v(const float* __restrict__ P3, unsigned short* __restrict__ VT) {
    int idx = blockIdx.x * 256 + threadIdx.x;  // 2*144*6400 exact
    int l = idx % 6400;
    int f = (idx / 6400) % 144;
    int g = idx / (144 * 6400);
    int ci = f / 9, kr = (f % 9) / 3, kc = f % 3;
    int oh = l / 80, ow = l % 80;
    int h = oh * 2 + kr - 1, w = ow * 2 + kc - 1;
    float v = 0.f;
    if (h >= 0 && h < 160 && w >= 0 && w < 160)
        v = P3[(size_t)(g * 48 + 32 + ci) * NPIX + h * 160 + w];
    VT[idx] = f2bf(v);
}

// ---------------- K3: MFMA flash attention (S^T = K@Q^T) ----------------
// Block: 256 thr = 4 waves, each wave 32 queries (block 128), keys split in 4
// ranges of 1600, iterated in tiles of 64. 32x32x16 bf16 MFMA throughout.
__global__ __launch_bounds__(256, 2) void k_attn(
    const unsigned short* __restrict__ PatQK, const unsigned short* __restrict__ VT,
    float* __restrict__ ml, unsigned short* __restrict__ Opart) {
    __shared__ unsigned short Ks[64 * 152];   // K tile, rows padded 144->152
    __shared__ unsigned short Vs[160 * 72];   // V^T tile, rows padded 64->72 (144..159 unused)
    __shared__ unsigned short Pl[4 * 32 * 72];// per-wave P^T as [q][k], rows padded

    int tid = threadIdx.x;
    int lane = tid & 63;
    int w = tid >> 6;
    int l31 = lane & 31;
    int h5 = lane >> 5;
    int split = blockIdx.y, g = blockIdx.z;
    int q = blockIdx.x * 128 + w * 32 + l31;

    const unsigned short* Qg = PatQK + ((size_t)g * 2 + 0) * 6400 * 144;
    const unsigned short* Kg = PatQK + ((size_t)g * 2 + 1) * 6400 * 144 + (size_t)split * 1600 * 144;
    const unsigned short* Vg = VT + (size_t)g * 144 * 6400 + split * 1600;

    // Q fragments (B operand) pinned in registers: lane reads its query row
    short8 qf[9];
#pragma unroll
    for (int fs = 0; fs < 9; fs++)
        qf[fs] = *(const short8*)(Qg + (size_t)q * 144 + fs * 16 + h5 * 8);

    floatx16 O[5];
#pragma unroll
    for (int i = 0; i < 5; i++) O[i] = (floatx16)0.f;
    float m = -1e30f, lsum = 0.f;

    unsigned short* Plw = Pl + w * (32 * 72);

    for (int it = 0; it < 25; it++) {
        __syncthreads();
        const unsigned short* Kt = Kg + it * 64 * 144;
        const unsigned short* Vtile = Vg + it * 64;
        for (int c = tid; c < 2304; c += 256) {
            if (c < 1152) {
                int row = c / 18, col = c - row * 18;
                *(short8*)&Ks[row * 152 + col * 8] = *(const short8*)(Kt + row * 144 + col * 8);
            } else {
                int vv = c - 1152;
                int f = vv >> 3, col = vv & 7;
                *(short8*)&Vs[f * 72 + col * 8] = *(const short8*)(Vtile + (size_t)f * 6400 + col * 8);
            }
        }
        __syncthreads();

        // S^T: two 32x32 C-tiles (keys 0-31 / 32-63), reduce over f=144 in 9 steps
        floatx16 S0 = (floatx16)0.f, S1 = (floatx16)0.f;
#pragma unroll
        for (int fs = 0; fs < 9; fs++) {
            short8 a0 = *(const short8*)&Ks[l31 * 152 + fs * 16 + h5 * 8];
            short8 a1 = *(const short8*)&Ks[(32 + l31) * 152 + fs * 16 + h5 * 8];
            S0 = __builtin_amdgcn_mfma_f32_32x32x16_bf16(a0, qf[fs], S0, 0, 0, 0);
            S1 = __builtin_amdgcn_mfma_f32_32x32x16_bf16(a1, qf[fs], S1, 0, 0, 0);
        }

        // online softmax: this lane's 32 scores all belong to query col=l31
        float mt = -1e30f;
#pragma unroll
        for (int r = 0; r < 16; r++) { mt = fmaxf(mt, S0[r]); mt = fmaxf(mt, S1[r]); }
        mt = fmaxf(mt, __shfl_xor(mt, 32, 64));
        float mnew = fmaxf(m, mt);
        float alpha = exp2f(LOG2E10 * (m - mnew));
        float ps = 0.f;
        float p0[16], p1[16];
#pragma unroll
        for (int r = 0; r < 16; r++) {
            p0[r] = exp2f(LOG2E10 * (S0[r] - mnew));
            p1[r] = exp2f(LOG2E10 * (S1[r] - mnew));
            ps += p0[r] + p1[r];
        }
        ps += __shfl_xor(ps, 32, 64);
        lsum = lsum * alpha + ps;
        m = mnew;
        if (__any(alpha < 1.f)) {
#pragma unroll
            for (int t5 = 0; t5 < 5; t5++)
#pragma unroll
                for (int r = 0; r < 16; r++) O[t5][r] *= alpha;
        }

        // P^T -> per-wave LDS as [q][k] bf16 (C rows: k = 8*rg + 4*h5 + rr, +32 tile1)
#pragma unroll
        for (int rg = 0; rg < 4; rg++) {
            ushort4 w0, w1;
            w0.x = f2bf(p0[4 * rg + 0]); w0.y = f2bf(p0[4 * rg + 1]);
            w0.z = f2bf(p0[4 * rg + 2]); w0.w = f2bf(p0[4 * rg + 3]);
            w1.x = f2bf(p1[4 * rg + 0]); w1.y = f2bf(p1[4 * rg + 1]);
            w1.z = f2bf(p1[4 * rg + 2]); w1.w = f2bf(p1[4 * rg + 3]);
            *(ushort4*)&Plw[l31 * 72 + rg * 8 + h5 * 4] = w0;
            *(ushort4*)&Plw[l31 * 72 + 32 + rg * 8 + h5 * 4] = w1;
        }

        // O^T += V^T @ P^T  (A from Vs, B from Plw; pad f-rows produce unused O rows)
#pragma unroll
        for (int ks = 0; ks < 4; ks++) {
            short8 pb = *(const short8*)&Plw[l31 * 72 + ks * 16 + h5 * 8];
#pragma unroll
            for (int ft = 0; ft < 5; ft++) {
                short8 va = *(const short8*)&Vs[(ft * 32 + l31) * 72 + ks * 16 + h5 * 8];
                O[ft] = __builtin_amdgcn_mfma_f32_32x32x16_bf16(va, pb, O[ft], 0, 0, 0);
            }
        }
    }

    if (h5 == 0)
        ((float2*)ml)[((size_t)g * 4 + split) * 6400 + q] = make_float2(m, lsum);

    unsigned short* Og = Opart + (((size_t)(g * 4 + split)) * 6400 + q) * 144;
#pragma unroll
    for (int ft = 0; ft < 5; ft++)
#pragma unroll
        for (int rg = 0; rg < 4; rg++) {
            int f = ft * 32 + rg * 8 + h5 * 4;
            if (f < 144) {
                ushort4 st;
                st.x = f2bf(O[ft][4 * rg + 0]); st.y = f2bf(O[ft][4 * rg + 1]);
                st.z = f2bf(O[ft][4 * rg + 2]); st.w = f2bf(O[ft][4 * rg + 3]);
                *(ushort4*)(Og + f) = st;
            }
        }
}

// ---------------- K3b: merge ksplit partials ----------------
__global__ void k_merge(const float* __restrict__ mlp, const unsigned short* __restrict__ Opart,
                        float* __restrict__ Zi) {
    int idx = blockIdx.x * 256 + threadIdx.x;  // 2*6400*36 exact
    int fg = idx % 36;
    int q = (idx / 36) % 6400;
    int g = idx / (36 * 6400);
    const float2* ml2 = (const float2*)mlp;
    float2 s[4];
#pragma unroll
    for (int k = 0; k < 4; k++) s[k] = ml2[((size_t)g * 4 + k) * 6400 + q];
    float ms = fmaxf(fmaxf(s[0].x, s[1].x), fmaxf(s[2].x, s[3].x));
    float wgt[4], denom = 0.f;
#pragma unroll
    for (int k = 0; k < 4; k++) {
        wgt[k] = exp2f(LOG2E10 * (s[k].x - ms));
        denom += wgt[k] * s[k].y;
    }
    float inv = 1.f / denom;
    float a0 = 0.f, a1 = 0.f, a2 = 0.f, a3 = 0.f;
#pragma unroll
    for (int k = 0; k < 4; k++) {
        ushort4 u = *(const ushort4*)(Opart + (((size_t)(g * 4 + k)) * 6400 + q) * 144 + fg * 4);
        a0 += wgt[k] * bf2f(u.x); a1 += wgt[k] * bf2f(u.y);
        a2 += wgt[k] * bf2f(u.z); a3 += wgt[k] * bf2f(u.w);
    }
    float4 out = make_float4(a0 * inv, a1 * inv, a2 * inv, a3 * inv);
    *(float4*)(Zi + ((size_t)g * 6400 + q) * 144 + fg * 4) = out;
}

// ---------------- K4: fold (overlap-add) + mask normalization ----------------
__global__ void k_fold(const float* __restrict__ Zi, float* __restrict__ zi2) {
    int idx = blockIdx.x * 256 + threadIdx.x;  // 2*16*25600 exact
    int pix = idx % NPIX;
    int ci = (idx / NPIX) & 15;
    int g = idx / (16 * NPIX);
    int h = pix / 160, w = pix % 160;
    int ohs[2], krs[2], nh = 0;
#pragma unroll
    for (int kr = 0; kr < 3; kr++) {
        int t = h + 1 - kr;
        if (t >= 0 && (t & 1) == 0 && (t >> 1) < 80) { ohs[nh] = t >> 1; krs[nh] = kr; nh++; }
    }
    int ows[2], kcs[2], nw = 0;
#pragma unroll
    for (int kc = 0; kc < 3; kc++) {
        int t = w + 1 - kc;
        if (t >= 0 && (t & 1) == 0 && (t >> 1) < 80) { ows[nw] = t >> 1; kcs[nw] = kc; nw++; }
    }
    float sm = 0.f;
    for (int a = 0; a < nh; a++)
        for (int bb = 0; bb < nw; bb++) {
            int l = ohs[a] * 80 + ows[bb];
            int f = ci * 9 + krs[a] * 3 + kcs[bb];
            sm += Zi[((size_t)g * 6400 + l) * 144 + f];
        }
    zi2[idx] = sm / (float)(nh * nw);
}

// ---------------- K5: out = b + conv1x1(zi2 broadcast over D) ----------------
__global__ void k_final(const float* __restrict__ b, const float* __restrict__ zi2,
                        const float* __restrict__ Ww, const float* __restrict__ Wb,
                        float* __restrict__ out) {
    __shared__ float z[16 * 64];
    __shared__ float Wl[64 * 16];
    __shared__ float Bl[64];
    int tid = threadIdx.x;
    int g = blockIdx.y;
    int pxb = blockIdx.x * 64;
    for (int i = tid; i < 1024; i += 256) {
        int ci = i >> 6, px = i & 63;
        z[i] = zi2[(size_t)(g * 16 + ci) * NPIX + pxb + px];
        Wl[i] = Ww[i];
    }
    if (tid < 64) Bl[tid] = Wb[tid];
    __syncthreads();

    int px4 = tid & 15;
    int cg = tid >> 4;
    float acc[4][4];
#pragma unroll
    for (int c4 = 0; c4 < 4; c4++) {
        float bv = Bl[cg + 16 * c4];
#pragma unroll
        for (int j = 0; j < 4; j++) acc[c4][j] = bv;
    }
#pragma unroll
    for (int ci = 0; ci < 16; ci++) {
        float zv[4];
#pragma unroll
        for (int j = 0; j < 4; j++) zv[j] = z[ci * 64 + px4 * 4 + j];
#pragma unroll
        for (int c4 = 0; c4 < 4; c4++) {
            float wv = Wl[(cg + 16 * c4) * 16 + ci];
#pragma unroll
            for (int j = 0; j < 4; j++) acc[c4][j] += wv * zv[j];
        }
    }
    for (int d = 0; d < 8; d++) {
#pragma unroll
        for (int c4 = 0; c4 < 4; c4++) {
            int c = cg + 16 * c4;
            size_t base = ((size_t)(g * 64 + c) * 8 + d) * NPIX + pxb + px4 * 4;
            float4 bv = *(const float4*)(b + base);
            float4 ov = make_float4(bv.x + acc[c4][0], bv.y + acc[c4][1],
                                    bv.z + acc[c4][2], bv.w + acc[c4][3]);
            *(float4*)(out + base) = ov;
        }
    }
}

extern "C" void kernel_launch(void* const* d_in, const int* in_sizes, int n_in,
                              void* d_out, int out_size, void* d_ws, size_t ws_size,
                              hipStream_t stream) {
    const float* b   = (const float*)d_in[0];
    const float* gw  = (const float*)d_in[1];
    const float* gb  = (const float*)d_in[2];
    const float* thw = (const float*)d_in[3];
    const float* thb = (const float*)d_in[4];
    const float* phw = (const float*)d_in[5];
    const float* phb = (const float*)d_in[6];
    const float* Ww  = (const float*)d_in[7];
    const float* Wb  = (const float*)d_in[8];
    float* out = (float*)d_out;
    float* ws = (float*)d_ws;

    unsigned short* PatQK = (unsigned short*)ws;                       // 3,686,400 bf16
    unsigned short* VT    = (unsigned short*)(ws + 1843200);           // 1,843,200 bf16
    float*          ml    = ws + 2764800;                              //   102,400 f32
    float*          P3    = ws + 2867200;                              // 2,457,600 f32
    unsigned short* Opart = (unsigned short*)(ws + 2867200);           // overlays P3
    float*          Zi    = ws;                                        // overlays PatQK
    float*          zi2   = ws + 1843200;                              // overlays VT

    k_proj<<<dim3(100, 2), 256, 0, stream>>>(b, gw, gb, thw, thb, phw, phb, P3);
    k_unfold_qk<<<dim3(14400), 256, 0, stream>>>(P3, PatQK);
    k_unfold_v<<<dim3(7200), 256, 0, stream>>>(P3, VT);
    k_attn<<<dim3(50, 4, 2), 256, 0, stream>>>(PatQK, VT, ml, Opart);
    k_merge<<<dim3(1800), 256, 0, stream>>>(ml, Opart, Zi);
    k_fold<<<dim3(3200), 256, 0, stream>>>(Zi, zi2);
    k_final<<<dim3(400, 2), 256, 0, stream>>>(b, zi2, Ww, Wb, out);
}